// Round 10
// baseline (209.879 us; speedup 1.0000x reference)
//
#include <hip/hip_runtime.h>
#include <hip/hip_bf16.h>
#include <stdint.h>

typedef __attribute__((ext_vector_type(8))) short bf16x8;
typedef __attribute__((ext_vector_type(4))) float f32x4;

#define S_2LOG2E 2.8853900817779268f   // 2*log2(e): tanh(x)=1-2/(2^(x*S)+1)

#if __has_builtin(__builtin_amdgcn_exp2f)
#define EXP2F(x) __builtin_amdgcn_exp2f(x)
#else
#define EXP2F(x) __expf((x) * 0.6931471805599453f)
#endif
#if __has_builtin(__builtin_amdgcn_rcpf)
#define RCPF(x) __builtin_amdgcn_rcpf(x)
#else
#define RCPF(x) (1.0f / (x))
#endif

// tanh given pre-scaled argument z = S*x : returns tanh(x)
__device__ __forceinline__ float tanh_z(float z) {
    float e = EXP2F(z);
    float r = RCPF(e + 1.0f);
    return fmaf(-2.0f, r, 1.0f);
}
__device__ __forceinline__ float tanh_fast(float x) {   // prep q only
    float e = __expf(2.0f * x);
    return 1.0f - 2.0f / (e + 1.0f);
}

// ---- bf16 pack via native v_cvt_pk_bf16_f32 (RNE) ----
__device__ __forceinline__ bf16x8 pack2(float4 a, float4 b) {
    union { bf16x8 v; __hip_bfloat162 h[4]; } r;
    r.h[0] = __float22bfloat162_rn(make_float2(a.x, a.y));
    r.h[1] = __float22bfloat162_rn(make_float2(a.z, a.w));
    r.h[2] = __float22bfloat162_rn(make_float2(b.x, b.y));
    r.h[3] = __float22bfloat162_rn(make_float2(b.z, b.w));
    return r.v;
}
__device__ __forceinline__ float4 scl4(float4 a) {      // fold S into W
    a.x *= S_2LOG2E; a.y *= S_2LOG2E; a.z *= S_2LOG2E; a.w *= S_2LOG2E;
    return a;
}
__device__ __forceinline__ float4 add4(float4 a, float4 b) {
    return make_float4(a.x + b.x, a.y + b.y, a.z + b.z, a.w + b.w);
}
__device__ __forceinline__ unsigned short f2bf(float x) {
    __hip_bfloat16 h = __float2bfloat16(x);
    return *reinterpret_cast<unsigned short*>(&h);
}
// bf16x8 -> 8 f32 (bf16->f32 is exact shift)
__device__ __forceinline__ void bf8f(bf16x8 v, float* f) {
    union { bf16x8 v; unsigned u[4]; } a; a.v = v;
#pragma unroll
    for (int i = 0; i < 4; ++i) {
        f[2 * i]     = __uint_as_float(a.u[i] << 16);
        f[2 * i + 1] = __uint_as_float(a.u[i] & 0xffff0000u);
    }
}
#define MFMA16(a, b, c) __builtin_amdgcn_mfma_f32_16x16x32_bf16((a), (b), (c), 0, 0, 0)

// =========================================================================
// Prep: [0,qb) q | qb biases | (qb,qb+8] wf cast (fallback only) |
// (qb+8,qb+48] zero out | [qb+49, +citb) Cit build | then Po build.
// Cit[i] = [ KT[i]=tanh(S*((attr+item_i)@Wk)+S*bk) (128 bf16) |
//            PiS[i]=S*(item_i@Wv) (128 bf16) ]      -- 512 B/row
// Po[o]  = S*(opin_o@Wv) (128 bf16).  B-frags built inline from f32 W
// (no wf_ws dependency -> no intra-kernel ordering race).
// =========================================================================
__global__ void finerec_prep(
    const float* __restrict__ user_emb, const float* __restrict__ attr,
    const float* __restrict__ Wq, const float* __restrict__ bq,
    const float* __restrict__ Wk, const float* __restrict__ bk,
    const float* __restrict__ Wv, const float* __restrict__ bv,
    const float* __restrict__ item_table, const float* __restrict__ opin_table,
    float* __restrict__ q_ws, float* __restrict__ bkz_ws, float* __restrict__ bvz_ws,
    short* __restrict__ wf_ws, short* __restrict__ cit, short* __restrict__ po_t,
    float* __restrict__ out, int U, int n_item, int n_opi, int qb)
{
    const int bx = blockIdx.x, tid = threadIdx.x;
    const int cb0 = qb + 49;
    if (bx >= cb0) {                         // ---- Cit / Po build ----
        const int citb = (n_item + 63) >> 6;
        const int wvp = tid >> 6, lane = tid & 63;
        const int l15 = lane & 15, quad = lane >> 4;
        const bool isPo = bx >= cb0 + citb;
        const int sj = ((bx - (isPo ? cb0 + citb : cb0)) << 2) + wvp;
        const int r0 = sj << 4;
        const int nrows = isPo ? n_opi : n_item;
        if (r0 >= nrows) return;
        const float* tbl = isPo ? opin_table : item_table;
        int ur = r0 + l15; if (ur >= nrows) ur = nrows - 1;
        const float* rp = tbl + (size_t)ur * 128 + quad * 8;
        bf16x8 afK[4], afV[4];
#pragma unroll
        for (int ks = 0; ks < 4; ++ks) {
            float4 ia = *(const float4*)(rp + ks * 32);
            float4 ib = *(const float4*)(rp + ks * 32 + 4);
            afV[ks] = pack2(ia, ib);
            if (!isPo) {
                float4 aa = *(const float4*)(attr + quad * 8 + ks * 32);
                float4 ab = *(const float4*)(attr + quad * 8 + ks * 32 + 4);
                afK[ks] = pack2(add4(ia, aa), add4(ib, ab));
            }
        }
#pragma unroll 1
        for (int nt = 0; nt < 8; ++nt) {
            const int n = nt * 16 + l15;
            f32x4 cV = {0, 0, 0, 0};
            f32x4 cK = {0, 0, 0, 0};
            if (!isPo) {
                const float bzk = bk[n] * S_2LOG2E;
                cK = (f32x4){bzk, bzk, bzk, bzk};
            }
#pragma unroll
            for (int ks = 0; ks < 4; ++ks) {
                const int co = (ks * 4 + quad) * 8;
                const float* wvpp = Wv + n * 128 + co;
                bf16x8 bV = pack2(scl4(*(const float4*)wvpp), scl4(*(const float4*)(wvpp + 4)));
                cV = MFMA16(afV[ks], bV, cV);
                if (!isPo) {
                    const float* wkp = Wk + n * 128 + co;
                    bf16x8 bK = pack2(scl4(*(const float4*)wkp), scl4(*(const float4*)(wkp + 4)));
                    cK = MFMA16(afK[ks], bK, cK);
                }
            }
#pragma unroll
            for (int r = 0; r < 4; ++r) {
                const int row = r0 + quad * 4 + r;
                if (row < nrows) {
                    if (isPo) {
                        ((unsigned short*)po_t)[(size_t)row * 128 + n] = f2bf(cV[r]);
                    } else {
                        unsigned short* crow = (unsigned short*)cit + (size_t)row * 256;
                        crow[n]       = f2bf(tanh_z(cK[r]));
                        crow[128 + n] = f2bf(cV[r]);
                    }
                }
            }
        }
        return;
    }
    if (bx >= qb + 9) {                      // ---- zero the atomic output ----
        const int gid = (bx - qb - 9) * 256 + tid;
        float4 z = {0.0f, 0.0f, 0.0f, 0.0f};
        for (int i = gid; i < U * 32; i += 40 * 256) ((float4*)out)[i] = z;
        return;
    }
    if (bx >= qb + 1) {                      // ---- wf cast (fallback main only) ----
        const int bi = bx - qb - 1;
#pragma unroll
        for (int t = 0; t < 2; ++t) {
            const int g = bi * 512 + t * 256 + tid;
            const int mat = g >> 11, gg = g & 2047, r = gg >> 4, c = gg & 15;
            const float* src = (mat ? Wv : Wk) + r * 128 + c * 8;
            ((bf16x8*)wf_ws)[(mat << 11) + (r << 4) + (c ^ (r & 15))] =
                pack2(scl4(*(const float4*)src), scl4(*(const float4*)(src + 4)));
        }
        return;
    }
    if (bx == qb) {                          // ---- pre-scaled biases ----
        if (tid < 128) {
            const float* wr = Wk + tid * 128;
            float s = bk[tid];
            for (int k = 0; k < 128; k += 4) {
                float4 w4 = *(const float4*)(wr + k);
                float4 a4 = *(const float4*)(attr + k);
                s += w4.x * a4.x + w4.y * a4.y + w4.z * a4.z + w4.w * a4.w;
            }
            bkz_ws[tid] = s * S_2LOG2E;
        } else if (tid < 256) {
            bvz_ws[tid - 128] = bv[tid - 128] * S_2LOG2E;
        }
        return;
    }
    // ---- q: 64 users per block (16 per wave) ----
    const int wv = tid >> 6, lane = tid & 63;
    const int l15 = lane & 15, quad = lane >> 4;
    const int u0 = (bx * 4 + wv) * 16;
    int ur = u0 + l15; if (ur >= U) ur = U - 1;
    const float* up = user_emb + (size_t)ur * 128 + quad * 8;
    bf16x8 af[4];
#pragma unroll
    for (int ks = 0; ks < 4; ++ks)
        af[ks] = pack2(*(const float4*)(up + ks * 32), *(const float4*)(up + ks * 32 + 4));
#pragma unroll
    for (int nt = 0; nt < 8; ++nt) {
        const int n = nt * 16 + l15;
        const float* wp = Wq + n * 128 + quad * 8;
        f32x4 acc = {0, 0, 0, 0};
#pragma unroll
        for (int ks = 0; ks < 4; ++ks) {
            bf16x8 bf = pack2(*(const float4*)(wp + ks * 32), *(const float4*)(wp + ks * 32 + 4));
            acc = MFMA16(af[ks], bf, acc);
        }
        const float bqv = bq[n];
#pragma unroll
        for (int r = 0; r < 4; ++r) {
            int row = u0 + quad * 4 + r;
            if (row < U) q_ws[row * 128 + nt * 16 + l15] = tanh_fast(acc[r] + bqv);
        }
    }
}

// =========================================================================
// Main2: GATHER-ONLY. Per 16-row job: w[row] = q . KT[idx] (VALU dot,
// row=l15, quad=col-block, 2-shfl reduce); v = tanh_z(PiS[idx]+PoS[od]+bvz)
// per element (row=quad*4+r, lane covers cols l15*8..+7); out += w*v with
// quad-reduce + 2 atomics. NO MFMA, NO LDS, NO syncthreads in steady state.
// Removes the per-occurrence MLP recompute (10x item / 100x opin redundant)
// and the DS pipe entirely. Split jobs (user boundary): unified q select in
// K; dual accT/accA in V.
// =========================================================================
template<int LC>
__global__ __launch_bounds__(1024) void finerec_main2(
    const int* __restrict__ item_seqs, const int* __restrict__ opin_seqs,
    const float* __restrict__ q_ws, const float* __restrict__ bvz_ws,
    const short* __restrict__ cit, const short* __restrict__ po_t,
    float* __restrict__ out, int U, int Lrt)
{
    const int L = LC ? LC : Lrt;
    const int tid = threadIdx.x;
    const int wv = tid >> 6, lane = tid & 63, l15 = lane & 15, quad = lane >> 4;
    const int UL = U * L;
    const int njobs = (UL + 15) >> 4;
    const int nwaves = gridDim.x * 16;

    // lane's bvz slice (cols l15*8..+7), L1-resident, job-invariant
    float bz[8];
    {
        float4 b0 = *(const float4*)(bvz_ws + l15 * 8);
        float4 b1 = *(const float4*)(bvz_ws + l15 * 8 + 4);
        bz[0] = b0.x; bz[1] = b0.y; bz[2] = b0.z; bz[3] = b0.w;
        bz[4] = b1.x; bz[5] = b1.y; bz[6] = b1.z; bz[7] = b1.w;
    }

#pragma unroll 1
    for (int job = blockIdx.x * 16 + wv; job < njobs; job += nwaves) {
        const int g0 = job << 4;
        const int uA = g0 / L;
        const int bb = L - (g0 - uA * L);    // rows of uA in this job
        const bool split = (bb < 16);        // bb<16 implies uA+1<U

        int vi = 0, vo = 0;
        if (lane < 16 && g0 + lane < UL) {
            vi = item_seqs[g0 + lane];
            vo = opin_seqs[g0 + lane];
        }
        const unsigned long long mb = __ballot(vi > 0);

        // ---- K: dot(q[qrow], KT[idx]) ; row = l15, quad covers 32 cols ----
        const int idx = __shfl(vi, l15);
        const int qrow = (l15 < bb) ? uA : uA + 1;
        const float* qp = q_ws + (size_t)qrow * 128 + quad * 32;
        const bf16x8* kp = (const bf16x8*)cit + (size_t)idx * 32 + quad * 4;
        float dot = 0.0f;
#pragma unroll
        for (int ks = 0; ks < 4; ++ks) {
            float kf[8]; bf8f(kp[ks], kf);
            const float4 qa = *(const float4*)(qp + ks * 8);
            const float4 qb4 = *(const float4*)(qp + ks * 8 + 4);
            dot = fmaf(kf[0], qa.x, dot);  dot = fmaf(kf[1], qa.y, dot);
            dot = fmaf(kf[2], qa.z, dot);  dot = fmaf(kf[3], qa.w, dot);
            dot = fmaf(kf[4], qb4.x, dot); dot = fmaf(kf[5], qb4.y, dot);
            dot = fmaf(kf[6], qb4.z, dot); dot = fmaf(kf[7], qb4.w, dot);
        }
        dot += __shfl_xor(dot, 16);
        dot += __shfl_xor(dot, 32);
        const float wrow = ((mb >> l15) & 1ull) ? dot : 0.0f;

        // ---- V: rows quad*4+r ; lane covers cols l15*8..+7 ----
        float* op = out + (size_t)uA * 128 + l15 * 8 + quad * 2;
        if (!split) {
            float acc[8] = {0, 0, 0, 0, 0, 0, 0, 0};
#pragma unroll
            for (int r = 0; r < 4; ++r) {
                const int rw = quad * 4 + r;
                const float wv_ = __shfl(wrow, rw);
                const int ir = __shfl(vi, rw);
                const int orr = __shfl(vo, rw);
                float pf[8], of[8];
                bf8f(*((const bf16x8*)cit + (size_t)ir * 32 + 16 + l15), pf);
                bf8f(*((const bf16x8*)po_t + (size_t)orr * 16 + l15), of);
#pragma unroll
                for (int j = 0; j < 8; ++j)
                    acc[j] = fmaf(wv_, tanh_z(pf[j] + of[j] + bz[j]), acc[j]);
            }
#pragma unroll
            for (int j = 0; j < 8; ++j) {
                acc[j] += __shfl_xor(acc[j], 16);
                acc[j] += __shfl_xor(acc[j], 32);
            }
            const float v0 = quad == 0 ? acc[0] : quad == 1 ? acc[2] : quad == 2 ? acc[4] : acc[6];
            const float v1 = quad == 0 ? acc[1] : quad == 1 ? acc[3] : quad == 2 ? acc[5] : acc[7];
            atomicAdd(op, v0);
            atomicAdd(op + 1, v1);
        } else {
            float accT[8] = {0, 0, 0, 0, 0, 0, 0, 0};
            float accA[8] = {0, 0, 0, 0, 0, 0, 0, 0};
#pragma unroll
            for (int r = 0; r < 4; ++r) {
                const int rw = quad * 4 + r;
                const float wv_ = __shfl(wrow, rw);
                const float wvA = (rw < bb) ? wv_ : 0.0f;
                const int ir = __shfl(vi, rw);
                const int orr = __shfl(vo, rw);
                float pf[8], of[8];
                bf8f(*((const bf16x8*)cit + (size_t)ir * 32 + 16 + l15), pf);
                bf8f(*((const bf16x8*)po_t + (size_t)orr * 16 + l15), of);
#pragma unroll
                for (int j = 0; j < 8; ++j) {
                    const float t = tanh_z(pf[j] + of[j] + bz[j]);
                    accT[j] = fmaf(wv_, t, accT[j]);
                    accA[j] = fmaf(wvA, t, accA[j]);
                }
            }
#pragma unroll
            for (int j = 0; j < 8; ++j) {
                accT[j] += __shfl_xor(accT[j], 16); accT[j] += __shfl_xor(accT[j], 32);
                accA[j] += __shfl_xor(accA[j], 16); accA[j] += __shfl_xor(accA[j], 32);
            }
            const float a0 = quad == 0 ? accA[0] : quad == 1 ? accA[2] : quad == 2 ? accA[4] : accA[6];
            const float a1 = quad == 0 ? accA[1] : quad == 1 ? accA[3] : quad == 2 ? accA[5] : accA[7];
            const float t0 = quad == 0 ? accT[0] : quad == 1 ? accT[2] : quad == 2 ? accT[4] : accT[6];
            const float t1 = quad == 0 ? accT[1] : quad == 1 ? accT[3] : quad == 2 ? accT[5] : accT[7];
            atomicAdd(op, a0);
            atomicAdd(op + 1, a1);
            atomicAdd(op + 128, t0 - a0);    // user uA+1
            atomicAdd(op + 129, t1 - a1);
        }
    }
}

// =========================================================================
// Fallback main (R1 structure, f32 gathers) — used only if ws too small.
// =========================================================================
template<int LC>
__global__ __launch_bounds__(1024, 4) void finerec_main(
    const float* __restrict__ item_table, const float* __restrict__ opin_table,
    const int* __restrict__ item_seqs, const int* __restrict__ opin_seqs,
    const float* __restrict__ q_ws, const float* __restrict__ bkz_ws,
    const float* __restrict__ bvz_ws, const short* __restrict__ wf_ws,
    float* __restrict__ out, int U, int Lrt)
{
    __shared__ __align__(16) short wlds[32768];
    __shared__ float bkz_lds[128], bvz_lds[128];

    const int L = LC ? LC : Lrt;
    const int tid = threadIdx.x;
    const int wv = tid >> 6, lane = tid & 63, l15 = lane & 15, quad = lane >> 4;

    const bf16x8* wsrc = (const bf16x8*)wf_ws;
    bf16x8* wldsv = (bf16x8*)wlds;
#pragma unroll
    for (int i = 0; i < 4; ++i)
        wldsv[i * 1024 + tid] = wsrc[i * 1024 + tid];
    if (tid < 128)      bkz_lds[tid]       = bkz_ws[tid];
    else if (tid < 256) bvz_lds[tid - 128] = bvz_ws[tid - 128];
    __syncthreads();

    const int UL = U * L;
    const int njobs = (UL + 15) >> 4;
    const int nwaves = gridDim.x * 16;

#pragma unroll 1
    for (int job = blockIdx.x * 16 + wv; job < njobs; job += nwaves) {
        const int g0 = job << 4;
        const int uA = g0 / L;
        const int bb = L - (g0 - uA * L);
        const bool split = (bb < 16) && (uA + 1 < U);

        int vi = 0, vo = 0;
        if (lane < 16 && g0 + lane < UL) {
            vi = item_seqs[g0 + lane];
            vo = opin_seqs[g0 + lane];
        }
        const unsigned long long mb = __ballot(vi > 0);

        const int idx = __shfl(vi, l15);
        bf16x8 ai[4];
        {
            const float* p = item_table + (size_t)idx * 128 + quad * 8;
#pragma unroll
            for (int ks = 0; ks < 4; ++ks)
                ai[ks] = pack2(*(const float4*)(p + ks * 32), *(const float4*)(p + ks * 32 + 4));
        }
        const float* qpA = q_ws + (size_t)uA * 128;
        float w[4] = {0, 0, 0, 0};
        if (!split) {
#pragma unroll 1
            for (int nt = 0; nt < 8; ++nt) {
                const int n = nt * 16 + l15;
                const float qa = qpA[n];
                const float bzv = bkz_lds[n];
                f32x4 c = {bzv, bzv, bzv, bzv};
#pragma unroll
                for (int ks = 0; ks < 4; ++ks)
                    c = MFMA16(ai[ks], wldsv[(n << 4) + ((ks * 4 + quad) ^ l15)], c);
#pragma unroll
                for (int r = 0; r < 4; ++r)
                    w[r] = fmaf(qa, tanh_z(c[r]), w[r]);
            }
        } else {
            const float* qpB = qpA + 128;
#pragma unroll 1
            for (int nt = 0; nt < 8; ++nt) {
                const int n = nt * 16 + l15;
                const float qa = qpA[n];
                const float qb2 = qpB[n];
                const float bzv = bkz_lds[n];
                f32x4 c = {bzv, bzv, bzv, bzv};
#pragma unroll
                for (int ks = 0; ks < 4; ++ks)
                    c = MFMA16(ai[ks], wldsv[(n << 4) + ((ks * 4 + quad) ^ l15)], c);
#pragma unroll
                for (int r = 0; r < 4; ++r) {
                    const float qv = (quad * 4 + r < bb) ? qa : qb2;
                    w[r] = fmaf(qv, tanh_z(c[r]), w[r]);
                }
            }
        }
#pragma unroll
        for (int r = 0; r < 4; ++r) {
            float t = w[r];
            t += __shfl_xor(t, 1); t += __shfl_xor(t, 2);
            t += __shfl_xor(t, 4); t += __shfl_xor(t, 8);
            w[r] = ((mb >> (quad * 4 + r)) & 1ull) ? t : 0.0f;
        }
        const int od = __shfl(vo, l15);
        bf16x8 ao[4];
        {
            const float* p = opin_table + (size_t)od * 128 + quad * 8;
#pragma unroll
            for (int ks = 0; ks < 4; ++ks)
                ao[ks] = pack2(*(const float4*)(p + ks * 32), *(const float4*)(p + ks * 32 + 4));
        }
        float* op = out + (size_t)uA * 128 + quad * 32 + l15;
        if (!split) {
            float s0 = 0.0f, s1 = 0.0f;
#pragma unroll 1
            for (int nt = 0; nt < 8; ++nt) {
                const int n = nt * 16 + l15;
                const float bzv = bvz_lds[n];
                f32x4 c = {bzv, bzv, bzv, bzv};
#pragma unroll
                for (int ks = 0; ks < 4; ++ks) {
                    const bf16x8 wf = wldsv[2048 + (n << 4) + ((ks * 4 + quad) ^ l15)];
                    c = MFMA16(ai[ks], wf, c);
                    c = MFMA16(ao[ks], wf, c);
                }
                float acc = 0.0f;
#pragma unroll
                for (int r = 0; r < 4; ++r)
                    acc = fmaf(w[r], tanh_z(c[r]), acc);
                acc += __shfl_xor(acc, 16);
                acc += __shfl_xor(acc, 32);
                const bool mine = (quad == (nt >> 1));
                s0 += (mine && !(nt & 1)) ? acc : 0.0f;
                s1 += (mine &&  (nt & 1)) ? acc : 0.0f;
            }
            atomicAdd(op, s0);
            atomicAdd(op + 16, s1);
        } else {
            float sA0 = 0.0f, sA1 = 0.0f, sB0 = 0.0f, sB1 = 0.0f;
#pragma unroll 1
            for (int nt = 0; nt < 8; ++nt) {
                const int n = nt * 16 + l15;
                const float bzv = bvz_lds[n];
                f32x4 c = {bzv, bzv, bzv, bzv};
#pragma unroll
                for (int ks = 0; ks < 4; ++ks) {
                    const bf16x8 wf = wldsv[2048 + (n << 4) + ((ks * 4 + quad) ^ l15)];
                    c = MFMA16(ai[ks], wf, c);
                    c = MFMA16(ao[ks], wf, c);
                }
                float accT = 0.0f, accA = 0.0f;
#pragma unroll
                for (int r = 0; r < 4; ++r) {
                    const float t = w[r] * tanh_z(c[r]);
                    accT += t;
                    accA += (quad * 4 + r < bb) ? t : 0.0f;
                }
                accT += __shfl_xor(accT, 16); accT += __shfl_xor(accT, 32);
                accA += __shfl_xor(accA, 16); accA += __shfl_xor(accA, 32);
                const float accB = accT - accA;
                const bool mine = (quad == (nt >> 1));
                const bool lo = !(nt & 1);
                sA0 += (mine && lo)  ? accA : 0.0f;
                sA1 += (mine && !lo) ? accA : 0.0f;
                sB0 += (mine && lo)  ? accB : 0.0f;
                sB1 += (mine && !lo) ? accB : 0.0f;
            }
            atomicAdd(op, sA0);
            atomicAdd(op + 16, sA1);
            atomicAdd(op + 128, sB0);
            atomicAdd(op + 144, sB1);
        }
    }
}

extern "C" void kernel_launch(void* const* d_in, const int* in_sizes, int n_in,
                              void* d_out, int out_size, void* d_ws, size_t ws_size,
                              hipStream_t stream) {
    const float* item_table = (const float*)d_in[0];
    const float* opin_table = (const float*)d_in[1];
    const float* user_emb   = (const float*)d_in[2];
    const float* attr       = (const float*)d_in[3];
    const float* Wq = (const float*)d_in[4];
    const float* bq = (const float*)d_in[5];
    const float* Wk = (const float*)d_in[6];
    const float* bk = (const float*)d_in[7];
    const float* Wv = (const float*)d_in[8];
    const float* bv = (const float*)d_in[9];
    const int* item_seqs = (const int*)d_in[10];
    const int* opin_seqs = (const int*)d_in[11];
    float* out = (float*)d_out;

    const int U = in_sizes[2] / 128;        // 10000
    const int L = in_sizes[10] / U;         // 50
    const int n_item = in_sizes[0] / 128;   // 50000
    const int n_opi  = in_sizes[1] / 128;   // 5000

    // ---- ws layout ----
    char* w = (char*)d_ws;
    float* q_ws   = (float*)w;               w += (size_t)U * 128 * 4;
    float* bkz_ws = (float*)w;               w += 512;
    float* bvz_ws = (float*)w;               w += 512;
    short* wf_ws  = (short*)w;               w += 4096 * 16;
    short* cit    = (short*)w;               w += (size_t)n_item * 256 * 2;  // KT|PiS
    short* po_t   = (short*)w;               w += (size_t)n_opi * 128 * 2;   // PoS
    const size_t need_new = (size_t)(w - (char*)d_ws);
    const int use_new = (ws_size >= need_new) ? 1 : 0;

    const int qb = (U + 63) / 64;
    const int citb = (n_item + 63) / 64;    // 64 rows/block (4 waves x 16)
    const int pob  = (n_opi + 63) / 64;
    const int prep_grid = qb + 49 + (use_new ? (citb + pob) : 0);
    finerec_prep<<<prep_grid, 256, 0, stream>>>(
        user_emb, attr, Wq, bq, Wk, bk, Wv, bv, item_table, opin_table,
        q_ws, bkz_ws, bvz_ws, wf_ws, cit, po_t, out, U, n_item, n_opi, qb);

    if (use_new) {
        if (L == 50)
            finerec_main2<50><<<512, 1024, 0, stream>>>(
                item_seqs, opin_seqs, q_ws, bvz_ws, cit, po_t, out, U, L);
        else
            finerec_main2<0><<<512, 1024, 0, stream>>>(
                item_seqs, opin_seqs, q_ws, bvz_ws, cit, po_t, out, U, L);
    } else {
        if (L == 50)
            finerec_main<50><<<512, 1024, 0, stream>>>(
                item_table, opin_table, item_seqs, opin_seqs,
                q_ws, bkz_ws, bvz_ws, wf_ws, out, U, L);
        else
            finerec_main<0><<<512, 1024, 0, stream>>>(
                item_table, opin_table, item_seqs, opin_seqs,
                q_ws, bkz_ws, bvz_ws, wf_ws, out, U, L);
    }
}